// Round 1
// 435.735 us; speedup vs baseline: 1.1053x; 1.1053x over previous
//
#include <hip/hip_runtime.h>
#include <hip/hip_bf16.h>
#include <math.h>

typedef unsigned short u16;
typedef unsigned int u32;
typedef __attribute__((ext_vector_type(8))) short short8;
typedef __attribute__((ext_vector_type(4))) float f32x4;

#define L_SEQ 4096
#define N_TOK 16384
#define D_MODEL 1024
#define R_DIM 16
#define PLU 120
#define G_DIM 256
#define K_CAT 1536  // 6 deltas * 256
#define K_GATE 2048

typedef __attribute__((address_space(1))) const void* as1cvp;
typedef __attribute__((address_space(3))) void* as3vp;
// async global->LDS, 16B per lane; LDS dest is wave-uniform base + lane*16
#define GLD16(g, l) \
  __builtin_amdgcn_global_load_lds((as1cvp)(g), (as3vp)(l), 16, 0, 0)

__device__ __forceinline__ u16 f2bf(float f) {
  u32 x = __float_as_uint(f);
  u32 lsb = (x >> 16) & 1u;
  x += 0x7fffu + lsb;
  return (u16)(x >> 16);
}
__device__ __forceinline__ float bf2f(u16 u) {
  return __uint_as_float(((u32)u) << 16);
}
__device__ __forceinline__ u32 pack2(float a, float b) {
  return (u32)f2bf(a) | ((u32)f2bf(b) << 16);
}

__device__ __forceinline__ void pair_from_k(int k, int& pi, int& pj) {
  int i = 0, kk = k, span = R_DIM - 1;
  while (kk >= span) { kk -= span; --span; ++i; }
  pi = i;
  pj = i + 1 + kk;
}

// ---- K_cvtT: fp32 [K x N] -> bf16 [N x Kp] transpose, zero-pad k in [K,Kp) -
__global__ __launch_bounds__(256) void k_cvtT(const float* __restrict__ src,
                                              u16* __restrict__ dst, int K,
                                              int Kp, int N) {
  __shared__ float t[32][33];
  const int k0 = blockIdx.y * 32, n0 = blockIdx.x * 32;
  const int r = threadIdx.x >> 3, c4 = (threadIdx.x & 7) * 4;
  float4 v = {0.f, 0.f, 0.f, 0.f};
  if (k0 + r < K) v = *(const float4*)(src + (size_t)(k0 + r) * N + n0 + c4);
  t[r][c4] = v.x;
  t[r][c4 + 1] = v.y;
  t[r][c4 + 2] = v.z;
  t[r][c4 + 3] = v.w;
  __syncthreads();
  uint2 o;
  o.x = pack2(t[c4][r], t[c4 + 1][r]);
  o.y = pack2(t[c4 + 2][r], t[c4 + 3][r]);
  *(uint2*)(dst + (size_t)(n0 + r) * Kp + k0 + c4) = o;
}

// -- K1: z = h @ red_w + red_b (N x 16 fp32); also emit h as bf16 (N x 1024) -
__global__ __launch_bounds__(256) void k_reduce(const float* __restrict__ h,
                                                const float* __restrict__ red_w,
                                                const float* __restrict__ red_b,
                                                float* __restrict__ z,
                                                u16* __restrict__ hb) {
  __shared__ alignas(16) u16 hs[16 * D_MODEL];  // 32 KB
  const int tid = threadIdx.x;
  const int t0 = blockIdx.x * 16;

  const float4* src = (const float4*)(h + (size_t)t0 * D_MODEL);
  u32* dst = (u32*)hs;
#pragma unroll
  for (int it = 0; it < (16 * D_MODEL / 4) / 256; ++it) {
    const int idx = tid + it * 256;
    const float4 v = src[idx];
    dst[idx * 2 + 0] = pack2(v.x, v.y);
    dst[idx * 2 + 1] = pack2(v.z, v.w);
  }
  __syncthreads();

  // write back bf16 h
  {
    const uint4* s4 = (const uint4*)hs;
    uint4* d4 = (uint4*)(hb + (size_t)t0 * D_MODEL);
#pragma unroll
    for (int it = 0; it < (16 * D_MODEL / 8) / 256; ++it)
      d4[tid + it * 256] = s4[tid + it * 256];
  }

  const int m = tid >> 4, c = tid & 15;
  const u16* hrow = hs + m * D_MODEL;
  float acc = 0.f;
#pragma unroll 8
  for (int i = 0; i < D_MODEL; i += 2) {
    u32 hv = *(const u32*)(hrow + i);
    float h0 = __uint_as_float(hv << 16);
    float h1 = __uint_as_float(hv & 0xffff0000u);
    acc = fmaf(h0, red_w[i * R_DIM + c], acc);
    acc = fmaf(h1, red_w[(i + 1) * R_DIM + c], acc);
  }
  z[(size_t)(t0 + m) * R_DIM + c] = acc + red_b[c];
}

// ---- K2 (MFMA): plucker -> GEMM1 -> gelu for all 6 deltas -> A_cat bf16 ----
__global__ __launch_bounds__(256) void k_plu(const float* __restrict__ z,
                                             const u16* __restrict__ W1t,
                                             const float* __restrict__ g1b,
                                             u16* __restrict__ A, int t0g) {
  __shared__ alignas(16) float zx[160][17];    // rows tg-32 .. tg+127
  __shared__ alignas(16) u16 W1s[128][136];    // [n][k], k padded 120->128
  __shared__ alignas(16) u16 Pb[128][136];     // [m][k] bf16, pad zeros
  __shared__ float prt[128][2];
  __shared__ float rno[128];
  __shared__ float b1s[128];
  __shared__ u32 pairs[PLU];

  const int tid = threadIdx.x, lane = tid & 63, w = tid >> 6;
  const int wm = w >> 1, wn = w & 1;
  const int n0 = blockIdx.x * 128;  // 0 or 128 of G_DIM
  const int tl = blockIdx.y * 128;  // local token base
  const int tg = t0g + tl;
  const int l0 = tg & (L_SEQ - 1);
  const int kq = (lane >> 4) * 8, mr = lane & 15;

  if (tid < PLU) {
    int pi, pj;
    pair_from_k(tid, pi, pj);
    pairs[tid] = (u32)pi | ((u32)pj << 8);
  }
  if (tid < 128) b1s[tid] = g1b[n0 + tid];
  for (int r = tid; r < 160 * 16; r += 256) {
    const int rr = r >> 4, c = r & 15;
    int t = tg - 32 + rr;
    if (t < 0) t = 0;
    zx[rr][c] = z[(size_t)t * R_DIM + c];
  }
  {
    const uint4* src = (const uint4*)(W1t + (size_t)n0 * 128);
    for (int i = tid; i < 128 * 16; i += 256) {
      const int r = i >> 4, c = i & 15;
      *(uint4*)&W1s[r][c * 8] = src[i];
    }
  }

  f32x4 acc[4][4];

#pragma unroll 1
  for (int dd = 0; dd < 6; ++dd) {
    const int delta = 1 << dd;
    __syncthreads();  // staging ready (dd=0); prior frag reads done (dd>0)
    {
      const int row = tid >> 1, half = tid & 1;
      const int kb = half * 60;
      const float* zc = zx[32 + row];
      const float* zpr = zx[32 + row - delta];
      float s = 0.f;
      for (int k = 0; k < 60; ++k) {
        const u32 pr = pairs[kb + k];
        const int pi = pr & 0xff, pj = pr >> 8;
        const float p = zpr[pi] * zc[pj] - zpr[pj] * zc[pi];
        s = fmaf(p, p, s);
        Pb[row][kb + k] = f2bf(p);
      }
      if (half) {  // zero-fill k = 120..127
        uint4 zz = {0u, 0u, 0u, 0u};
        *(uint4*)&Pb[row][120] = zz;
      }
      prt[row][half] = s;
    }
    __syncthreads();
    if (tid < 128) {
      const float s = prt[tid][0] + prt[tid][1];
      rno[tid] = 1.0f / fmaxf(sqrtf(s), 1e-6f);
    }
    __syncthreads();
#pragma unroll
    for (int a = 0; a < 4; ++a)
#pragma unroll
      for (int b = 0; b < 4; ++b) acc[a][b] = (f32x4)(0.f);
#pragma unroll
    for (int k0 = 0; k0 < 128; k0 += 32) {
      short8 af[4], bfr[4];
#pragma unroll
      for (int mi = 0; mi < 4; ++mi)
        af[mi] = *(const short8*)&Pb[wm * 64 + mi * 16 + mr][k0 + kq];
#pragma unroll
      for (int ni = 0; ni < 4; ++ni)
        bfr[ni] = *(const short8*)&W1s[wn * 64 + ni * 16 + mr][k0 + kq];
#pragma unroll
      for (int mi = 0; mi < 4; ++mi)
#pragma unroll
        for (int ni = 0; ni < 4; ++ni)
          acc[mi][ni] = __builtin_amdgcn_mfma_f32_16x16x32_bf16(
              af[mi], bfr[ni], acc[mi][ni], 0, 0, 0);
    }
#pragma unroll
    for (int mi = 0; mi < 4; ++mi) {
#pragma unroll
      for (int r = 0; r < 4; ++r) {
        const int rowl = wm * 64 + mi * 16 + (lane >> 4) * 4 + r;
        const bool ok = (l0 + rowl) >= delta;
        const float rn = rno[rowl];
#pragma unroll
        for (int ni = 0; ni < 4; ++ni) {
          const int colL = wn * 64 + ni * 16 + mr;
          const float x = acc[mi][ni][r] * rn + b1s[colL];
          const float ge = 0.5f * x * (1.0f + erff(x * 0.70710678118654752f));
          A[(size_t)(tl + rowl) * K_CAT + dd * G_DIM + n0 + colL] =
              ok ? f2bf(ge) : (u16)0;
        }
      }
    }
  }
}

// --- K3: MFMA GEMM  g = (A_cat @ W2_stacked + cnt*b2)/cnt  (ct x 1024 bf16) -
// m97 structure: 128x128 tile, BK=64, global_load_lds staging, XCD swizzle.
__global__ __launch_bounds__(256) void k_gemm2(const u16* __restrict__ A,
                                               const u16* __restrict__ W2t,
                                               const float* __restrict__ g2b,
                                               u16* __restrict__ g, int t0g) {
  __shared__ alignas(16) u16 As[128][64];
  __shared__ alignas(16) u16 Bs[128][64];
  const int tid = threadIdx.x, lane = tid & 63, w = tid >> 6;
  const int wm = w >> 1, wn = w & 1;

  // XCD-aware swizzle (bijective: gridDim.x % 8 == 0): each XCD owns a
  // contiguous M-range, N fastest so A-panels stay L2-hot.
  const int cpx = (int)gridDim.x >> 3;
  const int wi = ((int)blockIdx.x & 7) * cpx + ((int)blockIdx.x >> 3);
  const int n0 = (wi & 7) << 7;
  const int ml = (wi >> 3) << 7;

  const int lr = lane >> 3, lc = (lane & 7) << 3;  // lane row / u16 col
  const int rbase = (w << 5) + lr;                 // wave's staging row base
  const u16* a0 = A + (size_t)(ml + rbase) * K_CAT + lc;
  const u16* b0 = W2t + (size_t)(n0 + rbase) * G_DIM + lc;

  f32x4 acc[4][4];
#pragma unroll
  for (int a = 0; a < 4; ++a)
#pragma unroll
    for (int b = 0; b < 4; ++b) acc[a][b] = (f32x4)(0.f);

  const int kq = (lane >> 4) << 3, mr = lane & 15;

#pragma unroll 1
  for (int k0 = 0; k0 < K_CAT; k0 += 64) {
    const int kb = k0 & (G_DIM - 1);  // W2 tiles across the 6 delta blocks
#pragma unroll
    for (int it = 0; it < 4; ++it) {
      GLD16(a0 + (size_t)(it << 3) * K_CAT + k0, &As[(w << 5) + (it << 3)][0]);
      GLD16(b0 + (size_t)(it << 3) * G_DIM + kb, &Bs[(w << 5) + (it << 3)][0]);
    }
    __syncthreads();  // drains vmcnt(0) then barrier
#pragma unroll
    for (int kk = 0; kk < 64; kk += 32) {
      short8 af[4], bfr[4];
#pragma unroll
      for (int mi = 0; mi < 4; ++mi)
        af[mi] = *(const short8*)&As[wm * 64 + mi * 16 + mr][kk + kq];
#pragma unroll
      for (int ni = 0; ni < 4; ++ni)
        bfr[ni] = *(const short8*)&Bs[wn * 64 + ni * 16 + mr][kk + kq];
#pragma unroll
      for (int mi = 0; mi < 4; ++mi)
#pragma unroll
        for (int ni = 0; ni < 4; ++ni)
          acc[mi][ni] = __builtin_amdgcn_mfma_f32_16x16x32_bf16(
              af[mi], bfr[ni], acc[mi][ni], 0, 0, 0);
    }
    __syncthreads();  // LDS safe to overwrite
  }

  const int colb = n0 + wn * 64 + (lane & 15);
#pragma unroll
  for (int mi = 0; mi < 4; ++mi) {
#pragma unroll
    for (int r = 0; r < 4; ++r) {
      const int rowl = ml + wm * 64 + mi * 16 + (lane >> 4) * 4 + r;
      const int l = (t0g + rowl) & (L_SEQ - 1);
      const float cnt = (float)((l >= 1) + (l >= 2) + (l >= 4) + (l >= 8) +
                                (l >= 16) + (l >= 32));
      const float inv = 1.0f / fmaxf(cnt, 1.0f);
#pragma unroll
      for (int ni = 0; ni < 4; ++ni) {
        const int col = colb + ni * 16;
        const float v = (acc[mi][ni][r] + cnt * g2b[col]) * inv;
        g[(size_t)rowl * D_MODEL + col] = f2bf(v);
      }
    }
  }
}

// --- K4: MFMA gate: alpha=sigmoid([hb,g]@gate_w+b); out = a*h + (1-a)*g -----
// m97 structure: 128x128 tile, BK=64, global_load_lds staging, XCD swizzle.
__global__ __launch_bounds__(256) void k_gate(const u16* __restrict__ hb,
                                              const u16* __restrict__ g,
                                              const u16* __restrict__ WtG,
                                              const float* __restrict__ gb,
                                              float* __restrict__ out,
                                              int t0g) {
  __shared__ alignas(16) u16 As[128][64];
  __shared__ alignas(16) u16 Bs[128][64];
  const int tid = threadIdx.x, lane = tid & 63, w = tid >> 6;
  const int wm = w >> 1, wn = w & 1;

  const int cpx = (int)gridDim.x >> 3;
  const int wi = ((int)blockIdx.x & 7) * cpx + ((int)blockIdx.x >> 3);
  const int n0 = (wi & 7) << 7;
  const int ml = (wi >> 3) << 7;

  const int lr = lane >> 3, lc = (lane & 7) << 3;
  const int rbase = (w << 5) + lr;
  const u16* h0 = hb + (size_t)(t0g + ml + rbase) * D_MODEL + lc;
  const u16* g0 = g + (size_t)(ml + rbase) * D_MODEL + lc;
  const u16* b0 = WtG + (size_t)(n0 + rbase) * K_GATE + lc;

  f32x4 acc[4][4];
#pragma unroll
  for (int a = 0; a < 4; ++a)
#pragma unroll
    for (int b = 0; b < 4; ++b) acc[a][b] = (f32x4)(0.f);

  const int kq = (lane >> 4) << 3, mr = lane & 15;

#pragma unroll 1
  for (int k0 = 0; k0 < K_GATE; k0 += 64) {
    const u16* asrc = (k0 < D_MODEL) ? (h0 + k0) : (g0 + (k0 - D_MODEL));
    const u16* bsrc = b0 + k0;
#pragma unroll
    for (int it = 0; it < 4; ++it) {
      GLD16(asrc + (size_t)(it << 3) * D_MODEL, &As[(w << 5) + (it << 3)][0]);
      GLD16(bsrc + (size_t)(it << 3) * K_GATE, &Bs[(w << 5) + (it << 3)][0]);
    }
    __syncthreads();
#pragma unroll
    for (int kk = 0; kk < 64; kk += 32) {
      short8 af[4], bfr[4];
#pragma unroll
      for (int mi = 0; mi < 4; ++mi)
        af[mi] = *(const short8*)&As[wm * 64 + mi * 16 + mr][kk + kq];
#pragma unroll
      for (int ni = 0; ni < 4; ++ni)
        bfr[ni] = *(const short8*)&Bs[wn * 64 + ni * 16 + mr][kk + kq];
#pragma unroll
      for (int mi = 0; mi < 4; ++mi)
#pragma unroll
        for (int ni = 0; ni < 4; ++ni)
          acc[mi][ni] = __builtin_amdgcn_mfma_f32_16x16x32_bf16(
              af[mi], bfr[ni], acc[mi][ni], 0, 0, 0);
    }
    __syncthreads();
  }

  const int colb = n0 + wn * 64 + (lane & 15);
#pragma unroll
  for (int mi = 0; mi < 4; ++mi) {
#pragma unroll
    for (int r = 0; r < 4; ++r) {
      const int rowl = ml + wm * 64 + mi * 16 + (lane >> 4) * 4 + r;
      const size_t rowg = (size_t)(t0g + rowl) * D_MODEL;
#pragma unroll
      for (int ni = 0; ni < 4; ++ni) {
        const int col = colb + ni * 16;
        const float x = acc[mi][ni][r] + gb[col];
        const float al = 1.0f / (1.0f + expf(-x));
        const float hv = bf2f(hb[rowg + col]);
        const float gv = bf2f(g[(size_t)rowl * D_MODEL + col]);
        out[rowg + col] = fmaf(al, hv - gv, gv);
      }
    }
  }
}

// ---------------------------- launch ---------------------------------------
extern "C" void kernel_launch(void* const* d_in, const int* in_sizes, int n_in,
                              void* d_out, int out_size, void* d_ws,
                              size_t ws_size, hipStream_t stream) {
  const float* h = (const float*)d_in[0];
  const float* red_w = (const float*)d_in[1];
  const float* red_b = (const float*)d_in[2];
  const float* g1w = (const float*)d_in[3];
  const float* g1b = (const float*)d_in[4];
  const float* g2w = (const float*)d_in[5];
  const float* g2b = (const float*)d_in[6];
  const float* gate_w = (const float*)d_in[7];
  const float* gate_b = (const float*)d_in[8];
  float* out = (float*)d_out;

  const size_t sz_z = ((size_t)N_TOK * R_DIM * 4 + 255) & ~(size_t)255;
  const size_t sz_hb = (size_t)N_TOK * D_MODEL * 2;
  const size_t sz_WtG = (size_t)D_MODEL * K_GATE * 2;
  const size_t sz_W2t = (size_t)D_MODEL * G_DIM * 2;
  const size_t sz_W1t = (size_t)G_DIM * 128 * 2;
  const size_t fixed = sz_z + sz_hb + sz_WtG + sz_W2t + sz_W1t + 4096;

  int nc = 1;
  for (; nc <= 8; nc *= 2) {
    const size_t ct = N_TOK / nc;
    if (fixed + ct * (size_t)K_CAT * 2 + ct * (size_t)D_MODEL * 2 <= ws_size)
      break;
  }
  if (nc > 8) nc = 8;
  const int ct = N_TOK / nc;

  char* p = (char*)d_ws;
  float* z = (float*)p;
  p += sz_z;
  u16* hb = (u16*)p;
  p += sz_hb;
  u16* WtG = (u16*)p;
  p += sz_WtG;
  u16* W2t = (u16*)p;
  p += sz_W2t;
  u16* W1t = (u16*)p;
  p += sz_W1t;
  u16* Abuf = (u16*)p;
  p += (size_t)ct * K_CAT * 2;
  u16* gbuf = (u16*)p;

  k_reduce<<<dim3(N_TOK / 16), 256, 0, stream>>>(h, red_w, red_b, z, hb);
  k_cvtT<<<dim3(G_DIM / 32, 128 / 32), 256, 0, stream>>>(g1w, W1t, PLU, 128,
                                                         G_DIM);
  k_cvtT<<<dim3(D_MODEL / 32, G_DIM / 32), 256, 0, stream>>>(g2w, W2t, G_DIM,
                                                             G_DIM, D_MODEL);
  k_cvtT<<<dim3(D_MODEL / 32, K_GATE / 32), 256, 0, stream>>>(
      gate_w, WtG, K_GATE, K_GATE, D_MODEL);

  for (int c = 0; c < nc; ++c) {
    const int t0g = c * ct;
    k_plu<<<dim3(2, ct / 128), 256, 0, stream>>>(z, W1t, g1b, Abuf, t0g);
    k_gemm2<<<dim3(8 * (ct / 128)), 256, 0, stream>>>(Abuf, W2t, g2b, gbuf,
                                                      t0g);
    k_gate<<<dim3(8 * (ct / 128)), 256, 0, stream>>>(hb, gbuf, WtG, gate_b,
                                                     out, t0g);
  }
}